// Round 3
// baseline (1973.695 us; speedup 1.0000x reference)
//
#include <hip/hip_runtime.h>
#include <hip/hip_bf16.h>

#define IC 4096
#define OC 11008
#define MTOT 8192

typedef __attribute__((ext_vector_type(8))) short short8;
typedef __attribute__((ext_vector_type(4))) float floatx4;

// ---------------------------------------------------------------------------
// Fused dequant + GEMM, all f32 I/O (harness upcasts fp16 tensors to f32):
//   C[m,n] = sum_k x[m,k] * (q[n,k]*s[k/128,n] + z[k/128,n]) + bias[n]
// m97 geometry: 128x128 tile, BK=32, 4 waves (2x2), 16x16x32 bf16 MFMA.
// Both tiles register-staged with f32->bf16 / int->bf16 conversion, then
// ds_write_b128 into linear [row][32] bf16 LDS.
// ---------------------------------------------------------------------------
__global__ __launch_bounds__(256) void w4_gemm_fused_f32(
    const float* __restrict__ A,       // [8192][4096] f32 (upcast fp16)
    const int* __restrict__ Q,         // [11008][4096] int32 codes 0..15
    const float* __restrict__ scales,  // [32][11008] f32
    const float* __restrict__ zeros,   // [32][11008] f32
    const float* __restrict__ bias,    // [11008] f32
    float* __restrict__ C) {           // [8192][11008] f32
  __shared__ __hip_bfloat16 As[128 * 32];   // 8 KB
  __shared__ __hip_bfloat16 Bs[128 * 32];   // 8 KB

  const int NBN = OC / 128;                 // 86
  const int NBLK = (MTOT / 128) * NBN;      // 5504, divisible by 8
  int bid = blockIdx.x;
  int swz = (bid & 7) * (NBLK >> 3) + (bid >> 3);  // bijective XCD swizzle
  int bm = swz / NBN, bn = swz % NBN;
  const int m0 = bm * 128, n0 = bn * 128;

  const int tid = threadIdx.x;
  const int wid = tid >> 6, lane = tid & 63;
  const int wr = wid >> 1, wc = wid & 1;    // wave -> 64x64 sub-tile

  // staging geometry: thread covers row (tid>>1), k-half (tid&1)*16
  const int row = tid >> 1;                 // 0..127
  const int kh  = (tid & 1) * 16;           // 0 or 16

  const float* arow = A + (size_t)(m0 + row) * IC + kh;
  const int*   qrow = Q + (size_t)(n0 + row) * IC + kh;
  const int    nrow = n0 + row;

  // fragment read geometry (16x16x32: lane holds row l&15, k (l>>4)*8..+8)
  const int a_row = wr * 64 + (lane & 15);
  const int b_row = wc * 64 + (lane & 15);
  const int frag_kb = (lane >> 4) * 16;     // byte offset of k-slice

  floatx4 acc[4][4];
#pragma unroll
  for (int i = 0; i < 4; ++i)
#pragma unroll
    for (int j = 0; j < 4; ++j)
      acc[i][j] = (floatx4){0.f, 0.f, 0.f, 0.f};

  for (int k0 = 0; k0 < IC; k0 += 32) {
    // ---- load + convert A sub-row (16 f32 -> 16 bf16) ----
    float4 a0 = *(const float4*)(arow + k0);
    float4 a1 = *(const float4*)(arow + k0 + 4);
    float4 a2 = *(const float4*)(arow + k0 + 8);
    float4 a3 = *(const float4*)(arow + k0 + 12);

    // ---- load + dequant Q sub-row (16 int32 -> 16 bf16) ----
    int4 q0 = *(const int4*)(qrow + k0);
    int4 q1 = *(const int4*)(qrow + k0 + 4);
    int4 q2 = *(const int4*)(qrow + k0 + 8);
    int4 q3 = *(const int4*)(qrow + k0 + 12);
    int g = k0 >> 7;                        // quant group (32 | 128)
    float s = scales[(size_t)g * OC + nrow];
    float z = zeros[(size_t)g * OC + nrow];

    union { __hip_bfloat16 h[16]; short8 v[2]; } ua, ub;
    ua.h[0]  = __float2bfloat16(a0.x);  ua.h[1]  = __float2bfloat16(a0.y);
    ua.h[2]  = __float2bfloat16(a0.z);  ua.h[3]  = __float2bfloat16(a0.w);
    ua.h[4]  = __float2bfloat16(a1.x);  ua.h[5]  = __float2bfloat16(a1.y);
    ua.h[6]  = __float2bfloat16(a1.z);  ua.h[7]  = __float2bfloat16(a1.w);
    ua.h[8]  = __float2bfloat16(a2.x);  ua.h[9]  = __float2bfloat16(a2.y);
    ua.h[10] = __float2bfloat16(a2.z);  ua.h[11] = __float2bfloat16(a2.w);
    ua.h[12] = __float2bfloat16(a3.x);  ua.h[13] = __float2bfloat16(a3.y);
    ua.h[14] = __float2bfloat16(a3.z);  ua.h[15] = __float2bfloat16(a3.w);

    ub.h[0]  = __float2bfloat16(fmaf((float)q0.x, s, z));
    ub.h[1]  = __float2bfloat16(fmaf((float)q0.y, s, z));
    ub.h[2]  = __float2bfloat16(fmaf((float)q0.z, s, z));
    ub.h[3]  = __float2bfloat16(fmaf((float)q0.w, s, z));
    ub.h[4]  = __float2bfloat16(fmaf((float)q1.x, s, z));
    ub.h[5]  = __float2bfloat16(fmaf((float)q1.y, s, z));
    ub.h[6]  = __float2bfloat16(fmaf((float)q1.z, s, z));
    ub.h[7]  = __float2bfloat16(fmaf((float)q1.w, s, z));
    ub.h[8]  = __float2bfloat16(fmaf((float)q2.x, s, z));
    ub.h[9]  = __float2bfloat16(fmaf((float)q2.y, s, z));
    ub.h[10] = __float2bfloat16(fmaf((float)q2.z, s, z));
    ub.h[11] = __float2bfloat16(fmaf((float)q2.w, s, z));
    ub.h[12] = __float2bfloat16(fmaf((float)q3.x, s, z));
    ub.h[13] = __float2bfloat16(fmaf((float)q3.y, s, z));
    ub.h[14] = __float2bfloat16(fmaf((float)q3.z, s, z));
    ub.h[15] = __float2bfloat16(fmaf((float)q3.w, s, z));

    *(short8*)(&As[row * 32 + kh])     = ua.v[0];
    *(short8*)(&As[row * 32 + kh + 8]) = ua.v[1];
    *(short8*)(&Bs[row * 32 + kh])     = ub.v[0];
    *(short8*)(&Bs[row * 32 + kh + 8]) = ub.v[1];

    __syncthreads();   // LDS writes visible to all waves

    short8 af[4], bf[4];
#pragma unroll
    for (int fm = 0; fm < 4; ++fm)
      af[fm] = *(const short8*)((const char*)As + (a_row + fm * 16) * 64 + frag_kb);
#pragma unroll
    for (int fn = 0; fn < 4; ++fn)
      bf[fn] = *(const short8*)((const char*)Bs + (b_row + fn * 16) * 64 + frag_kb);

#pragma unroll
    for (int fm = 0; fm < 4; ++fm)
#pragma unroll
      for (int fn = 0; fn < 4; ++fn)
        acc[fm][fn] = __builtin_amdgcn_mfma_f32_16x16x32_bf16(
            af[fm], bf[fn], acc[fm][fn], 0, 0, 0);

    __syncthreads();   // protect LDS before next iteration overwrites
  }

  // ---- epilogue: bias + f32 store ----
#pragma unroll
  for (int fn = 0; fn < 4; ++fn) {
    int n = n0 + wc * 64 + fn * 16 + (lane & 15);
    float bv = bias[n];
#pragma unroll
    for (int fm = 0; fm < 4; ++fm) {
      int mrow = m0 + wr * 64 + fm * 16 + (lane >> 4) * 4;
#pragma unroll
      for (int j = 0; j < 4; ++j) {
        C[(size_t)(mrow + j) * OC + n] = acc[fm][fn][j] + bv;
      }
    }
  }
}

extern "C" void kernel_launch(void* const* d_in, const int* in_sizes, int n_in,
                              void* d_out, int out_size, void* d_ws, size_t ws_size,
                              hipStream_t stream) {
  const float* x      = (const float*)d_in[0];   // fp16 ref -> f32 buffer
  const int*   qw     = (const int*)d_in[1];
  const float* scales = (const float*)d_in[2];
  const float* szeros = (const float*)d_in[3];
  const float* bias   = (const float*)d_in[4];
  float* out = (float*)d_out;                    // fp16 ref output -> f32 buffer
  (void)d_ws; (void)ws_size;

  // GEMM grid: (8192/128) x (11008/128) = 64 x 86 = 5504 blocks
  w4_gemm_fused_f32<<<5504, 256, 0, stream>>>(x, qw, scales, szeros, bias, out);
}

// Round 4
// 1064.507 us; speedup vs baseline: 1.8541x; 1.8541x over previous
//
#include <hip/hip_runtime.h>
#include <hip/hip_bf16.h>

#define IC 4096
#define OC 11008
#define MTOT 8192

typedef __attribute__((ext_vector_type(8))) short short8;
typedef __attribute__((ext_vector_type(4))) float floatx4;

// ---------------------------------------------------------------------------
// Pass 1a: convert x f32 -> bf16 (8 elems/thread)
// ---------------------------------------------------------------------------
__global__ __launch_bounds__(256) void cvt_x_kernel(
    const float* __restrict__ X, __hip_bfloat16* __restrict__ Xb) {
  size_t base = ((size_t)blockIdx.x * 256 + threadIdx.x) * 8;
  float4 a0 = *(const float4*)(X + base);
  float4 a1 = *(const float4*)(X + base + 4);
  union { __hip_bfloat16 h[8]; short8 v; } u;
  u.h[0] = __float2bfloat16(a0.x); u.h[1] = __float2bfloat16(a0.y);
  u.h[2] = __float2bfloat16(a0.z); u.h[3] = __float2bfloat16(a0.w);
  u.h[4] = __float2bfloat16(a1.x); u.h[5] = __float2bfloat16(a1.y);
  u.h[6] = __float2bfloat16(a1.z); u.h[7] = __float2bfloat16(a1.w);
  *(short8*)(Xb + base) = u.v;
}

// ---------------------------------------------------------------------------
// Pass 1b: dequant Q int32 -> bf16 W [OC][IC]  (8 elems/thread)
// w[o,k] = q[o,k]*scales[k/128,o] + zeros[k/128,o]
// ---------------------------------------------------------------------------
__global__ __launch_bounds__(256) void dequant_kernel(
    const int* __restrict__ Q, const float* __restrict__ scales,
    const float* __restrict__ zeros, __hip_bfloat16* __restrict__ W) {
  size_t base = ((size_t)blockIdx.x * 256 + threadIdx.x) * 8;
  int o = (int)(base >> 12);             // / 4096
  int g = ((int)(base & 4095)) >> 7;     // group (8 elems same group)
  float s = scales[(size_t)g * OC + o];
  float z = zeros[(size_t)g * OC + o];
  int4 q0 = *(const int4*)(Q + base);
  int4 q1 = *(const int4*)(Q + base + 4);
  union { __hip_bfloat16 h[8]; short8 v; } u;
  u.h[0] = __float2bfloat16(fmaf((float)q0.x, s, z));
  u.h[1] = __float2bfloat16(fmaf((float)q0.y, s, z));
  u.h[2] = __float2bfloat16(fmaf((float)q0.z, s, z));
  u.h[3] = __float2bfloat16(fmaf((float)q0.w, s, z));
  u.h[4] = __float2bfloat16(fmaf((float)q1.x, s, z));
  u.h[5] = __float2bfloat16(fmaf((float)q1.y, s, z));
  u.h[6] = __float2bfloat16(fmaf((float)q1.z, s, z));
  u.h[7] = __float2bfloat16(fmaf((float)q1.w, s, z));
  *(short8*)(W + base) = u.v;
}

// ---------------------------------------------------------------------------
// Pass 2: C[m,n] = sum_k Xb[m,k]*W[n,k] + bias[n]  (bf16 B^T GEMM, m97)
// 128x128 tile, BK=32, 4 waves (2x2), global_load_lds width-16 staging.
// ---------------------------------------------------------------------------
__device__ __forceinline__ void async_copy16(const void* g, void* l) {
  __builtin_amdgcn_global_load_lds(
      (const __attribute__((address_space(1))) void*)g,
      (__attribute__((address_space(3))) void*)l, 16, 0, 0);
}

__global__ __launch_bounds__(256) void gemm_bt_kernel(
    const __hip_bfloat16* __restrict__ A,   // [8192][4096] bf16
    const __hip_bfloat16* __restrict__ B,   // [11008][4096] bf16
    const float* __restrict__ bias,         // [11008] f32
    float* __restrict__ C) {                // [8192][11008] f32
  __shared__ __hip_bfloat16 As[128 * 32];   // 8 KB, linear [row][k]
  __shared__ __hip_bfloat16 Bs[128 * 32];   // 8 KB, linear [n][k]

  const int NBN = OC / 128;                 // 86
  const int NBLK = (MTOT / 128) * NBN;      // 5504, divisible by 8
  int bid = blockIdx.x;
  int swz = (bid & 7) * (NBLK >> 3) + (bid >> 3);  // bijective XCD swizzle
  int bm = swz / NBN, bn = swz % NBN;
  const int m0 = bm * 128, n0 = bn * 128;

  const int tid = threadIdx.x;
  const int wid = tid >> 6, lane = tid & 63;
  const int wr = wid >> 1, wc = wid & 1;    // wave -> 64x64 sub-tile

  // staging: lane l of segment s covers LDS bytes s*1024 + l*16
  const int srow = lane >> 2;               // row within 16-row segment
  const int scol = (lane & 3) * 8;          // k element offset

  // fragment geometry (16x16x32: lane holds row l&15, k (l>>4)*8..+8)
  const int a_row = wr * 64 + (lane & 15);
  const int b_row = wc * 64 + (lane & 15);
  const int frag_kb = (lane >> 4) * 16;

  floatx4 acc[4][4];
#pragma unroll
  for (int i = 0; i < 4; ++i)
#pragma unroll
    for (int j = 0; j < 4; ++j)
      acc[i][j] = (floatx4){0.f, 0.f, 0.f, 0.f};

  for (int k0 = 0; k0 < IC; k0 += 32) {
#pragma unroll
    for (int i = 0; i < 2; ++i) {
      int s = wid * 2 + i;                  // segment 0..7
      const __hip_bfloat16* ga =
          A + (size_t)(m0 + s * 16 + srow) * IC + k0 + scol;
      async_copy16(ga, (char*)As + s * 1024);
      const __hip_bfloat16* gb =
          B + (size_t)(n0 + s * 16 + srow) * IC + k0 + scol;
      async_copy16(gb, (char*)Bs + s * 1024);
    }
    __syncthreads();

    short8 af[4], bf[4];
#pragma unroll
    for (int fm = 0; fm < 4; ++fm)
      af[fm] = *(const short8*)((const char*)As + (a_row + fm * 16) * 64 + frag_kb);
#pragma unroll
    for (int fn = 0; fn < 4; ++fn)
      bf[fn] = *(const short8*)((const char*)Bs + (b_row + fn * 16) * 64 + frag_kb);

#pragma unroll
    for (int fm = 0; fm < 4; ++fm)
#pragma unroll
      for (int fn = 0; fn < 4; ++fn)
        acc[fm][fn] = __builtin_amdgcn_mfma_f32_16x16x32_bf16(
            af[fm], bf[fn], acc[fm][fn], 0, 0, 0);

    __syncthreads();
  }

#pragma unroll
  for (int fn = 0; fn < 4; ++fn) {
    int n = n0 + wc * 64 + fn * 16 + (lane & 15);
    float bv = bias[n];
#pragma unroll
    for (int fm = 0; fm < 4; ++fm) {
      int mrow = m0 + wr * 64 + fm * 16 + (lane >> 4) * 4;
#pragma unroll
      for (int j = 0; j < 4; ++j) {
        C[(size_t)(mrow + j) * OC + n] = acc[fm][fn][j] + bv;
      }
    }
  }
}

// ---------------------------------------------------------------------------
// Fallback: fused dequant+GEMM (round-3 passing kernel), used if ws too small
// ---------------------------------------------------------------------------
__global__ __launch_bounds__(256) void w4_gemm_fused_f32(
    const float* __restrict__ A, const int* __restrict__ Q,
    const float* __restrict__ scales, const float* __restrict__ zeros,
    const float* __restrict__ bias, float* __restrict__ C) {
  __shared__ __hip_bfloat16 As[128 * 32];
  __shared__ __hip_bfloat16 Bs[128 * 32];

  const int NBN = OC / 128;
  const int NBLK = (MTOT / 128) * NBN;
  int bid = blockIdx.x;
  int swz = (bid & 7) * (NBLK >> 3) + (bid >> 3);
  int bm = swz / NBN, bn = swz % NBN;
  const int m0 = bm * 128, n0 = bn * 128;

  const int tid = threadIdx.x;
  const int wid = tid >> 6, lane = tid & 63;
  const int wr = wid >> 1, wc = wid & 1;

  const int row = tid >> 1;
  const int kh  = (tid & 1) * 16;

  const float* arow = A + (size_t)(m0 + row) * IC + kh;
  const int*   qrow = Q + (size_t)(n0 + row) * IC + kh;
  const int    nrow = n0 + row;

  const int a_row = wr * 64 + (lane & 15);
  const int b_row = wc * 64 + (lane & 15);
  const int frag_kb = (lane >> 4) * 16;

  floatx4 acc[4][4];
#pragma unroll
  for (int i = 0; i < 4; ++i)
#pragma unroll
    for (int j = 0; j < 4; ++j)
      acc[i][j] = (floatx4){0.f, 0.f, 0.f, 0.f};

  for (int k0 = 0; k0 < IC; k0 += 32) {
    float4 a0 = *(const float4*)(arow + k0);
    float4 a1 = *(const float4*)(arow + k0 + 4);
    float4 a2 = *(const float4*)(arow + k0 + 8);
    float4 a3 = *(const float4*)(arow + k0 + 12);
    int4 q0 = *(const int4*)(qrow + k0);
    int4 q1 = *(const int4*)(qrow + k0 + 4);
    int4 q2 = *(const int4*)(qrow + k0 + 8);
    int4 q3 = *(const int4*)(qrow + k0 + 12);
    int g = k0 >> 7;
    float s = scales[(size_t)g * OC + nrow];
    float z = zeros[(size_t)g * OC + nrow];

    union { __hip_bfloat16 h[16]; short8 v[2]; } ua, ub;
    ua.h[0]  = __float2bfloat16(a0.x);  ua.h[1]  = __float2bfloat16(a0.y);
    ua.h[2]  = __float2bfloat16(a0.z);  ua.h[3]  = __float2bfloat16(a0.w);
    ua.h[4]  = __float2bfloat16(a1.x);  ua.h[5]  = __float2bfloat16(a1.y);
    ua.h[6]  = __float2bfloat16(a1.z);  ua.h[7]  = __float2bfloat16(a1.w);
    ua.h[8]  = __float2bfloat16(a2.x);  ua.h[9]  = __float2bfloat16(a2.y);
    ua.h[10] = __float2bfloat16(a2.z);  ua.h[11] = __float2bfloat16(a2.w);
    ua.h[12] = __float2bfloat16(a3.x);  ua.h[13] = __float2bfloat16(a3.y);
    ua.h[14] = __float2bfloat16(a3.z);  ua.h[15] = __float2bfloat16(a3.w);
    ub.h[0]  = __float2bfloat16(fmaf((float)q0.x, s, z));
    ub.h[1]  = __float2bfloat16(fmaf((float)q0.y, s, z));
    ub.h[2]  = __float2bfloat16(fmaf((float)q0.z, s, z));
    ub.h[3]  = __float2bfloat16(fmaf((float)q0.w, s, z));
    ub.h[4]  = __float2bfloat16(fmaf((float)q1.x, s, z));
    ub.h[5]  = __float2bfloat16(fmaf((float)q1.y, s, z));
    ub.h[6]  = __float2bfloat16(fmaf((float)q1.z, s, z));
    ub.h[7]  = __float2bfloat16(fmaf((float)q1.w, s, z));
    ub.h[8]  = __float2bfloat16(fmaf((float)q2.x, s, z));
    ub.h[9]  = __float2bfloat16(fmaf((float)q2.y, s, z));
    ub.h[10] = __float2bfloat16(fmaf((float)q2.z, s, z));
    ub.h[11] = __float2bfloat16(fmaf((float)q2.w, s, z));
    ub.h[12] = __float2bfloat16(fmaf((float)q3.x, s, z));
    ub.h[13] = __float2bfloat16(fmaf((float)q3.y, s, z));
    ub.h[14] = __float2bfloat16(fmaf((float)q3.z, s, z));
    ub.h[15] = __float2bfloat16(fmaf((float)q3.w, s, z));

    *(short8*)(&As[row * 32 + kh])     = ua.v[0];
    *(short8*)(&As[row * 32 + kh + 8]) = ua.v[1];
    *(short8*)(&Bs[row * 32 + kh])     = ub.v[0];
    *(short8*)(&Bs[row * 32 + kh + 8]) = ub.v[1];

    __syncthreads();

    short8 af[4], bf[4];
#pragma unroll
    for (int fm = 0; fm < 4; ++fm)
      af[fm] = *(const short8*)((const char*)As + (a_row + fm * 16) * 64 + frag_kb);
#pragma unroll
    for (int fn = 0; fn < 4; ++fn)
      bf[fn] = *(const short8*)((const char*)Bs + (b_row + fn * 16) * 64 + frag_kb);

#pragma unroll
    for (int fm = 0; fm < 4; ++fm)
#pragma unroll
      for (int fn = 0; fn < 4; ++fn)
        acc[fm][fn] = __builtin_amdgcn_mfma_f32_16x16x32_bf16(
            af[fm], bf[fn], acc[fm][fn], 0, 0, 0);

    __syncthreads();
  }

#pragma unroll
  for (int fn = 0; fn < 4; ++fn) {
    int n = n0 + wc * 64 + fn * 16 + (lane & 15);
    float bv = bias[n];
#pragma unroll
    for (int fm = 0; fm < 4; ++fm) {
      int mrow = m0 + wr * 64 + fm * 16 + (lane >> 4) * 4;
#pragma unroll
      for (int j = 0; j < 4; ++j) {
        C[(size_t)(mrow + j) * OC + n] = acc[fm][fn][j] + bv;
      }
    }
  }
}

extern "C" void kernel_launch(void* const* d_in, const int* in_sizes, int n_in,
                              void* d_out, int out_size, void* d_ws, size_t ws_size,
                              hipStream_t stream) {
  const float* x      = (const float*)d_in[0];   // fp16 ref -> f32 buffer
  const int*   qw     = (const int*)d_in[1];
  const float* scales = (const float*)d_in[2];
  const float* szeros = (const float*)d_in[3];
  const float* bias   = (const float*)d_in[4];
  float* out = (float*)d_out;

  const size_t wbytes = (size_t)OC * IC * 2;     // 90,177,536
  const size_t xbytes = (size_t)MTOT * IC * 2;   // 67,108,864

  if (ws_size >= wbytes + xbytes) {
    __hip_bfloat16* W  = (__hip_bfloat16*)d_ws;
    __hip_bfloat16* Xb = (__hip_bfloat16*)((char*)d_ws + wbytes);
    // 33,554,432 / 8 / 256 = 16384 blocks
    cvt_x_kernel<<<16384, 256, 0, stream>>>(x, Xb);
    // 45,088,768 / 8 / 256 = 22016 blocks
    dequant_kernel<<<22016, 256, 0, stream>>>(qw, scales, szeros, W);
    // (8192/128) x (11008/128) = 5504 blocks
    gemm_bt_kernel<<<5504, 256, 0, stream>>>(Xb, W, bias, out);
  } else {
    w4_gemm_fused_f32<<<5504, 256, 0, stream>>>(x, qw, scales, szeros, bias, out);
  }
}

// Round 5
// 755.563 us; speedup vs baseline: 2.6122x; 1.4089x over previous
//
#include <hip/hip_runtime.h>
#include <hip/hip_bf16.h>

#define IC 4096
#define OC 11008
#define MTOT 8192

#define BM 256
#define BN 256
#define BK 64
#define NT (IC / BK)      // 64 K-tiles
#define LDSBUF 65536      // one buffer: A 32 KB + B 32 KB
#define BOFF 32768

typedef __attribute__((ext_vector_type(8))) short short8;
typedef __attribute__((ext_vector_type(4))) float floatx4;

__device__ __forceinline__ void async_copy16(const void* g, void* l) {
  __builtin_amdgcn_global_load_lds(
      (const __attribute__((address_space(1))) void*)g,
      (__attribute__((address_space(3))) void*)l, 16, 0, 0);
}

#define CFENCE() asm volatile("" ::: "memory")
#define BARRIER() do { CFENCE(); __builtin_amdgcn_s_barrier(); CFENCE(); } while (0)

// ---------------------------------------------------------------------------
// Pass 1a: x f32 -> bf16
// ---------------------------------------------------------------------------
__global__ __launch_bounds__(256) void cvt_x_kernel(
    const float* __restrict__ X, __hip_bfloat16* __restrict__ Xb) {
  size_t base = ((size_t)blockIdx.x * 256 + threadIdx.x) * 8;
  float4 a0 = *(const float4*)(X + base);
  float4 a1 = *(const float4*)(X + base + 4);
  union { __hip_bfloat16 h[8]; short8 v; } u;
  u.h[0] = __float2bfloat16(a0.x); u.h[1] = __float2bfloat16(a0.y);
  u.h[2] = __float2bfloat16(a0.z); u.h[3] = __float2bfloat16(a0.w);
  u.h[4] = __float2bfloat16(a1.x); u.h[5] = __float2bfloat16(a1.y);
  u.h[6] = __float2bfloat16(a1.z); u.h[7] = __float2bfloat16(a1.w);
  *(short8*)(Xb + base) = u.v;
}

// ---------------------------------------------------------------------------
// Pass 1b: dequant Q int32 -> bf16 W [OC][IC]
// ---------------------------------------------------------------------------
__global__ __launch_bounds__(256) void dequant_kernel(
    const int* __restrict__ Q, const float* __restrict__ scales,
    const float* __restrict__ zeros, __hip_bfloat16* __restrict__ W) {
  size_t base = ((size_t)blockIdx.x * 256 + threadIdx.x) * 8;
  int o = (int)(base >> 12);
  int g = ((int)(base & 4095)) >> 7;
  float s = scales[(size_t)g * OC + o];
  float z = zeros[(size_t)g * OC + o];
  int4 q0 = *(const int4*)(Q + base);
  int4 q1 = *(const int4*)(Q + base + 4);
  union { __hip_bfloat16 h[8]; short8 v; } u;
  u.h[0] = __float2bfloat16(fmaf((float)q0.x, s, z));
  u.h[1] = __float2bfloat16(fmaf((float)q0.y, s, z));
  u.h[2] = __float2bfloat16(fmaf((float)q0.z, s, z));
  u.h[3] = __float2bfloat16(fmaf((float)q0.w, s, z));
  u.h[4] = __float2bfloat16(fmaf((float)q1.x, s, z));
  u.h[5] = __float2bfloat16(fmaf((float)q1.y, s, z));
  u.h[6] = __float2bfloat16(fmaf((float)q1.z, s, z));
  u.h[7] = __float2bfloat16(fmaf((float)q1.w, s, z));
  *(short8*)(W + base) = u.v;
}

// ---------------------------------------------------------------------------
// Pass 2: 256x256x64 8-wave 4-phase-per-K-tile pipelined GEMM (T2+T3+T4+T5).
// C[m,n] = sum_k A[m,k]*B[n,k] + bias[n].
// LDS: 2 buffers x (A 32K + B 32K), XOR-swizzled rows (byte ^= (row&7)<<4),
// staged via global_load_lds with pre-swizzled global source (rule #21).
// B-fragments register-held per K-tile -> B LDS region free after phase 0,
// enabling tile t+2 prefetch into the current buffer (vmcnt(6) steady state).
// ---------------------------------------------------------------------------
__global__ __launch_bounds__(512, 2) void gemm_8phase(
    const __hip_bfloat16* __restrict__ A,   // [MTOT][IC] bf16
    const __hip_bfloat16* __restrict__ B,   // [OC][IC] bf16
    const float* __restrict__ bias,         // [OC] f32
    float* __restrict__ C) {                // [MTOT][OC] f32
  __shared__ char lds[2 * LDSBUF];          // 128 KB

  const int NBN = OC / BN;                  // 43
  const int NBLK = (MTOT / BM) * NBN;       // 1376 (divisible by 8)
  int bid = blockIdx.x;
  int swz = (bid & 7) * (NBLK >> 3) + (bid >> 3);
  int bm = swz / NBN, bn = swz % NBN;
  const int m0 = bm * BM, n0 = bn * BN;

  const int tid  = threadIdx.x;
  const int lane = tid & 63;
  const int wid  = tid >> 6;
  const int wr = wid >> 2, wc = wid & 3;    // 2x4 wave grid; wave owns 128x64

  // ---- staging geometry: unit = 64 rows x 128 B = 8 KB = 1 load/thread ----
  const int srl   = tid >> 3;               // row within unit (0..63)
  const int scph  = (tid & 7) << 4;         // physical col byte (0..112)
  const int sclog = scph ^ ((srl & 7) << 4);// pre-swizzled logical col byte
  const char* gA = (const char*)A + ((size_t)(m0 + srl) * IC) * 2 + sclog;
  const char* gB = (const char*)B + ((size_t)(n0 + srl) * IC) * 2 + sclog;
  const size_t UROW = (size_t)64 * IC * 2;  // global byte stride per unit
  const int sdst = tid * 16;                // linear LDS dest within unit

  // ---- fragment-read geometry (16x16x32; lane: row l&15, k (l>>4)*8) ----
  const int l15  = lane & 15;
  const int hi16 = ((lane >> 4) & 3) << 4;
  const int swzl = (lane & 7) << 4;         // (row&7)<<4 == (lane&7)<<4
  const int ck0  = hi16 ^ swzl;             // col byte for kk=0 (kk=1: ^64)
  const int aRowB = (wr * 128 + l15) * 128; // row byte offset in A region
  const int bRowB = (wc * 64  + l15) * 128; // row byte offset in B region

  floatx4 acc[8][4];
#pragma unroll
  for (int i = 0; i < 8; ++i)
#pragma unroll
    for (int j = 0; j < 4; ++j)
      acc[i][j] = (floatx4){0.f, 0.f, 0.f, 0.f};

  // ---- prologue: tile0 complete (8 units) + tile1 partial (B0-3,A0,A2) ----
#pragma unroll
  for (int u = 0; u < 4; ++u)
    async_copy16(gA + u * UROW, lds + u * 8192 + sdst);
#pragma unroll
  for (int u = 0; u < 4; ++u)
    async_copy16(gB + u * UROW, lds + BOFF + u * 8192 + sdst);
#pragma unroll
  for (int u = 0; u < 4; ++u)
    async_copy16(gB + u * UROW + 128, lds + LDSBUF + BOFF + u * 8192 + sdst);
  async_copy16(gA + 0 * UROW + 128, lds + LDSBUF + 0 * 8192 + sdst);
  async_copy16(gA + 2 * UROW + 128, lds + LDSBUF + 2 * 8192 + sdst);
  asm volatile("s_waitcnt vmcnt(6)" ::: "memory");  // tile0 landed
  BARRIER();

  for (int t = 0; t < NT; ++t) {
    const int par = t & 1;
    char* curA = lds + par * LDSBUF;
    char* curB = curA + BOFF;
    char* nxtA = lds + (par ^ 1) * LDSBUF;
    const char* gAt1 = gA + (size_t)(t + 1) * 128;
    const char* gAt2 = gA + (size_t)(t + 2) * 128;
    const char* gBt2 = gB + (size_t)(t + 2) * 128;
    const bool s1 = (t + 1 < NT), s2 = (t + 2 < NT);

    const char* pa = curA + aRowB;
    const char* pb = curB + bRowB;
    short8 bfr[4][2];

#define MFMA16(P, AF0, AF1, AF2, AF3)                                        \
    BARRIER();                                                               \
    asm volatile("s_waitcnt lgkmcnt(0)" ::: "memory");                       \
    __builtin_amdgcn_s_setprio(1);                                           \
    _Pragma("unroll")                                                        \
    for (int fn = 0; fn < 4; ++fn) {                                         \
      acc[2*(P)][fn]   = __builtin_amdgcn_mfma_f32_16x16x32_bf16(            \
          AF0, bfr[fn][0], acc[2*(P)][fn], 0, 0, 0);                         \
      acc[2*(P)][fn]   = __builtin_amdgcn_mfma_f32_16x16x32_bf16(            \
          AF1, bfr[fn][1], acc[2*(P)][fn], 0, 0, 0);                         \
      acc[2*(P)+1][fn] = __builtin_amdgcn_mfma_f32_16x16x32_bf16(            \
          AF2, bfr[fn][0], acc[2*(P)+1][fn], 0, 0, 0);                       \
      acc[2*(P)+1][fn] = __builtin_amdgcn_mfma_f32_16x16x32_bf16(            \
          AF3, bfr[fn][1], acc[2*(P)+1][fn], 0, 0, 0);                       \
    }                                                                        \
    __builtin_amdgcn_s_setprio(0);

    // ---------- phase 0: fm 0-1; read all B frags; stage t+1 A1,A3 ----------
    {
      short8 a00 = *(const short8*)(pa + 0 * 2048 + ck0);
      short8 a01 = *(const short8*)(pa + 0 * 2048 + (ck0 ^ 64));
      short8 a10 = *(const short8*)(pa + 1 * 2048 + ck0);
      short8 a11 = *(const short8*)(pa + 1 * 2048 + (ck0 ^ 64));
#pragma unroll
      for (int fn = 0; fn < 4; ++fn) {
        bfr[fn][0] = *(const short8*)(pb + fn * 2048 + ck0);
        bfr[fn][1] = *(const short8*)(pb + fn * 2048 + (ck0 ^ 64));
      }
      if (s1) {
        async_copy16(gAt1 + 1 * UROW, nxtA + 1 * 8192 + sdst);
        async_copy16(gAt1 + 3 * UROW, nxtA + 3 * 8192 + sdst);
      }
      MFMA16(0, a00, a01, a10, a11);
      BARRIER();
    }
    // ---------- phase 1: fm 2-3; stage t+2 B0,B1 (B free after p0) ----------
    {
      short8 a00 = *(const short8*)(pa + 2 * 2048 + ck0);
      short8 a01 = *(const short8*)(pa + 2 * 2048 + (ck0 ^ 64));
      short8 a10 = *(const short8*)(pa + 3 * 2048 + ck0);
      short8 a11 = *(const short8*)(pa + 3 * 2048 + (ck0 ^ 64));
      if (s2) {
        async_copy16(gBt2 + 0 * UROW, curB + 0 * 8192 + sdst);
        async_copy16(gBt2 + 1 * UROW, curB + 1 * 8192 + sdst);
      }
      MFMA16(1, a00, a01, a10, a11);
      BARRIER();
    }
    // ---------- phase 2: fm 4-5; stage t+2 B2,B3 ----------
    {
      short8 a00 = *(const short8*)(pa + 4 * 2048 + ck0);
      short8 a01 = *(const short8*)(pa + 4 * 2048 + (ck0 ^ 64));
      short8 a10 = *(const short8*)(pa + 5 * 2048 + ck0);
      short8 a11 = *(const short8*)(pa + 5 * 2048 + (ck0 ^ 64));
      if (s2) {
        async_copy16(gBt2 + 2 * UROW, curB + 2 * 8192 + sdst);
        async_copy16(gBt2 + 3 * UROW, curB + 3 * 8192 + sdst);
      }
      MFMA16(2, a00, a01, a10, a11);
      BARRIER();
    }
    // ---------- phase 3: fm 6-7; stage t+2 A0,A2 (rows 0-63,128-191:
    //            last read at p0/p1, drained by p1's lgkmcnt+barrier) --------
    {
      short8 a00 = *(const short8*)(pa + 6 * 2048 + ck0);
      short8 a01 = *(const short8*)(pa + 6 * 2048 + (ck0 ^ 64));
      short8 a10 = *(const short8*)(pa + 7 * 2048 + ck0);
      short8 a11 = *(const short8*)(pa + 7 * 2048 + (ck0 ^ 64));
      if (s2) {
        async_copy16(gAt2 + 0 * UROW, curA + 0 * 8192 + sdst);
        async_copy16(gAt2 + 2 * UROW, curA + 2 * 8192 + sdst);
      }
      MFMA16(3, a00, a01, a10, a11);
      // iteration-end sync: tile t+1 must be fully landed; keep t+2's 6
      // units (issued p1-p3) in flight -> counted vmcnt, never 0 mid-loop.
      if (s2)      { asm volatile("s_waitcnt vmcnt(6)" ::: "memory"); }
      else if (s1) { asm volatile("s_waitcnt vmcnt(0)" ::: "memory"); }
      BARRIER();
    }
#undef MFMA16
  }

  // ---- epilogue: bias + f32 store ----
#pragma unroll
  for (int fn = 0; fn < 4; ++fn) {
    int n = n0 + wc * 64 + fn * 16 + l15;
    float bv = bias[n];
#pragma unroll
    for (int fm = 0; fm < 8; ++fm) {
      int mrow = m0 + wr * 128 + fm * 16 + ((lane >> 4) << 2);
#pragma unroll
      for (int j = 0; j < 4; ++j)
        C[(size_t)(mrow + j) * OC + n] = acc[fm][fn][j] + bv;
    }
  }
}

// ---------------------------------------------------------------------------
// Fallback (ws too small): round-3 verified fused kernel
// ---------------------------------------------------------------------------
__global__ __launch_bounds__(256) void w4_gemm_fused_f32(
    const float* __restrict__ A, const int* __restrict__ Q,
    const float* __restrict__ scales, const float* __restrict__ zeros,
    const float* __restrict__ bias, float* __restrict__ C) {
  __shared__ __hip_bfloat16 As[128 * 32];
  __shared__ __hip_bfloat16 Bs[128 * 32];
  const int NBN = OC / 128;
  const int NBLK = (MTOT / 128) * NBN;
  int bid = blockIdx.x;
  int swz = (bid & 7) * (NBLK >> 3) + (bid >> 3);
  int bm = swz / NBN, bn = swz % NBN;
  const int m0 = bm * 128, n0 = bn * 128;
  const int tid = threadIdx.x;
  const int wid = tid >> 6, lane = tid & 63;
  const int wr = wid >> 1, wc = wid & 1;
  const int row = tid >> 1;
  const int kh  = (tid & 1) * 16;
  const float* arow = A + (size_t)(m0 + row) * IC + kh;
  const int*   qrow = Q + (size_t)(n0 + row) * IC + kh;
  const int    nrow = n0 + row;
  const int a_row = wr * 64 + (lane & 15);
  const int b_row = wc * 64 + (lane & 15);
  const int frag_kb = (lane >> 4) * 16;
  floatx4 acc[4][4];
#pragma unroll
  for (int i = 0; i < 4; ++i)
#pragma unroll
    for (int j = 0; j < 4; ++j)
      acc[i][j] = (floatx4){0.f, 0.f, 0.f, 0.f};
  for (int k0 = 0; k0 < IC; k0 += 32) {
    float4 a0 = *(const float4*)(arow + k0);
    float4 a1 = *(const float4*)(arow + k0 + 4);
    float4 a2 = *(const float4*)(arow + k0 + 8);
    float4 a3 = *(const float4*)(arow + k0 + 12);
    int4 q0 = *(const int4*)(qrow + k0);
    int4 q1 = *(const int4*)(qrow + k0 + 4);
    int4 q2 = *(const int4*)(qrow + k0 + 8);
    int4 q3 = *(const int4*)(qrow + k0 + 12);
    int g = k0 >> 7;
    float s = scales[(size_t)g * OC + nrow];
    float z = zeros[(size_t)g * OC + nrow];
    union { __hip_bfloat16 h[16]; short8 v[2]; } ua, ub;
    ua.h[0]=__float2bfloat16(a0.x); ua.h[1]=__float2bfloat16(a0.y);
    ua.h[2]=__float2bfloat16(a0.z); ua.h[3]=__float2bfloat16(a0.w);
    ua.h[4]=__float2bfloat16(a1.x); ua.h[5]=__float2bfloat16(a1.y);
    ua.h[6]=__float2bfloat16(a1.z); ua.h[7]=__float2bfloat16(a1.w);
    ua.h[8]=__float2bfloat16(a2.x); ua.h[9]=__float2bfloat16(a2.y);
    ua.h[10]=__float2bfloat16(a2.z); ua.h[11]=__float2bfloat16(a2.w);
    ua.h[12]=__float2bfloat16(a3.x); ua.h[13]=__float2bfloat16(a3.y);
    ua.h[14]=__float2bfloat16(a3.z); ua.h[15]=__float2bfloat16(a3.w);
    ub.h[0]=__float2bfloat16(fmaf((float)q0.x,s,z));
    ub.h[1]=__float2bfloat16(fmaf((float)q0.y,s,z));
    ub.h[2]=__float2bfloat16(fmaf((float)q0.z,s,z));
    ub.h[3]=__float2bfloat16(fmaf((float)q0.w,s,z));
    ub.h[4]=__float2bfloat16(fmaf((float)q1.x,s,z));
    ub.h[5]=__float2bfloat16(fmaf((float)q1.y,s,z));
    ub.h[6]=__float2bfloat16(fmaf((float)q1.z,s,z));
    ub.h[7]=__float2bfloat16(fmaf((float)q1.w,s,z));
    ub.h[8]=__float2bfloat16(fmaf((float)q2.x,s,z));
    ub.h[9]=__float2bfloat16(fmaf((float)q2.y,s,z));
    ub.h[10]=__float2bfloat16(fmaf((float)q2.z,s,z));
    ub.h[11]=__float2bfloat16(fmaf((float)q2.w,s,z));
    ub.h[12]=__float2bfloat16(fmaf((float)q3.x,s,z));
    ub.h[13]=__float2bfloat16(fmaf((float)q3.y,s,z));
    ub.h[14]=__float2bfloat16(fmaf((float)q3.z,s,z));
    ub.h[15]=__float2bfloat16(fmaf((float)q3.w,s,z));
    *(short8*)(&As[row * 32 + kh])     = ua.v[0];
    *(short8*)(&As[row * 32 + kh + 8]) = ua.v[1];
    *(short8*)(&Bs[row * 32 + kh])     = ub.v[0];
    *(short8*)(&Bs[row * 32 + kh + 8]) = ub.v[1];
    __syncthreads();
    short8 af[4], bf[4];
#pragma unroll
    for (int fm = 0; fm < 4; ++fm)
      af[fm] = *(const short8*)((const char*)As + (a_row + fm*16)*64 + frag_kb);
#pragma unroll
    for (int fn = 0; fn < 4; ++fn)
      bf[fn] = *(const short8*)((const char*)Bs + (b_row + fn*16)*64 + frag_kb);
#pragma unroll
    for (int fm = 0; fm < 4; ++fm)
#pragma unroll
      for (int fn = 0; fn < 4; ++fn)
        acc[fm][fn] = __builtin_amdgcn_mfma_f32_16x16x32_bf16(
            af[fm], bf[fn], acc[fm][fn], 0, 0, 0);
    __syncthreads();
  }
#pragma unroll
  for (int fn = 0; fn < 4; ++fn) {
    int n = n0 + wc * 64 + fn * 16 + (lane & 15);
    float bv = bias[n];
#pragma unroll
    for (int fm = 0; fm < 4; ++fm) {
      int mrow = m0 + wr * 64 + fm * 16 + (lane >> 4) * 4;
#pragma unroll
      for (int j = 0; j < 4; ++j)
        C[(size_t)(mrow + j) * OC + n] = acc[fm][fn][j] + bv;
    }
  }
}

extern "C" void kernel_launch(void* const* d_in, const int* in_sizes, int n_in,
                              void* d_out, int out_size, void* d_ws, size_t ws_size,
                              hipStream_t stream) {
  const float* x      = (const float*)d_in[0];
  const int*   qw     = (const int*)d_in[1];
  const float* scales = (const float*)d_in[2];
  const float* szeros = (const float*)d_in[3];
  const float* bias   = (const float*)d_in[4];
  float* out = (float*)d_out;

  const size_t wbytes = (size_t)OC * IC * 2;
  const size_t xbytes = (size_t)MTOT * IC * 2;

  if (ws_size >= wbytes + xbytes) {
    __hip_bfloat16* W  = (__hip_bfloat16*)d_ws;
    __hip_bfloat16* Xb = (__hip_bfloat16*)((char*)d_ws + wbytes);
    cvt_x_kernel<<<16384, 256, 0, stream>>>(x, Xb);
    dequant_kernel<<<22016, 256, 0, stream>>>(qw, scales, szeros, W);
    gemm_8phase<<<1376, 512, 0, stream>>>(Xb, W, bias, out);
  } else {
    w4_gemm_fused_f32<<<5504, 256, 0, stream>>>(x, qw, scales, szeros, bias, out);
  }
}